// Round 12
// baseline (78.530 us; speedup 1.0000x reference)
//
#include <hip/hip_runtime.h>
#include <hip/hip_bf16.h>

typedef __attribute__((ext_vector_type(8))) short bf16x8;
typedef __attribute__((ext_vector_type(4))) float f32x4;
typedef __attribute__((ext_vector_type(4))) int   i32x4;
typedef __attribute__((ext_vector_type(2))) int   i32x2;

#define DEV static __device__ __forceinline__

DEV unsigned short f2bf(float f) {
  __hip_bfloat16 h = __float2bfloat16(f);
  return __builtin_bit_cast(unsigned short, h);
}
DEV int pack2(float a, float b) {
  return (int)f2bf(a) | ((int)f2bf(b) << 16);
}
DEV bf16x8 ldsFrag(const char* p, int off) {
  i32x4 v = *(const i32x4*)(p + off);
  return __builtin_bit_cast(bf16x8, v);
}

// Tiled operand layout: each 1KB tile = one MFMA fragment set for a full wave,
// lane-linear (lane l's 16B at tile_base + l*16B).
// A-frag tile [16 rows][32 k]: lane l -> (row = l&15, k = (l>>4)*8 + j)
// B-frag tile [16 cols][32 k]: identical order.

// ---------------- pre-kernel (unchanged) ----------------
__global__ __launch_bounds__(256) void cvt_all(
    const float* __restrict__ x, unsigned short* __restrict__ xt,
    const float* __restrict__ sw, unsigned short* __restrict__ swb,
    const float* __restrict__ tw, unsigned short* __restrict__ twb)
{
  const int bid = blockIdx.x;
  const int tid = threadIdx.x;
  if (bid < 512) {
    __shared__ unsigned short lt[64][72];
    const int ut = bid & 3;
    const int mt = (bid >> 2) & 7;
    const int bc = bid >> 5;
    const int ul = tid & 63;
    const int mr = tid >> 6;
    const float* px = x + ((size_t)bc * 512 + mt * 64) * 256 + ut * 64;
#pragma unroll
    for (int r = 0; r < 16; r++) {
      int m = r * 4 + mr;
      lt[m][ul] = f2bf(px[(size_t)m * 256 + ul]);
    }
    __syncthreads();
    const int t8 = tid >> 5;
    const int a  = t8 & 3;
    const int bb = t8 >> 2;
    const int l0 = tid & 31;
    unsigned short* tilep =
        xt + (((size_t)(bc * 16 + ut * 4 + a)) * 16 + (mt * 2 + bb)) * 512;
#pragma unroll
    for (int h = 0; h < 2; h++) {
      int l = l0 + h * 32;
      int ur = a * 16 + (l & 15);
      int mb = bb * 32 + (l >> 4) * 8;
      i32x4 w;
#pragma unroll
      for (int j = 0; j < 4; j++)
        w[j] = (int)lt[mb + 2 * j][ur] | ((int)lt[mb + 2 * j + 1][ur] << 16);
      *(i32x4*)(tilep + l * 8) = w;
    }
  } else if (bid < 1024) {
    const int tile = (bid - 512) * 4 + (tid >> 6);
    const int l = tid & 63;
    const int mt2 = tile & 15;
    const int nt2 = (tile >> 4) & 31;
    const int p   = tile >> 9;
    const float* ps = sw + ((size_t)p * 512 + nt2 * 16 + (l & 15)) * 512
                         + mt2 * 32 + (l >> 4) * 8;
    f32x4 A = ((const f32x4*)ps)[0], Bv = ((const f32x4*)ps)[1];
    i32x4 w;
    w[0] = pack2(A[0], A[1]);  w[1] = pack2(A[2], A[3]);
    w[2] = pack2(Bv[0], Bv[1]); w[3] = pack2(Bv[2], Bv[3]);
    *(i32x4*)(swb + (size_t)tile * 512 + l * 8) = w;
  } else {
    const int tile = (bid - 1024) * 4 + (tid >> 6);
    const int l = tid & 63;
    const int ut2 = tile & 7;
    const int tt2 = (tile >> 3) & 15;
    const int q   = tile >> 7;
    const float* pt = tw + ((size_t)q * 256 + tt2 * 16 + (l & 15)) * 256
                         + ut2 * 32 + (l >> 4) * 8;
    f32x4 A = ((const f32x4*)pt)[0], Bv = ((const f32x4*)pt)[1];
    i32x4 w;
    w[0] = pack2(A[0], A[1]);  w[1] = pack2(A[2], A[3]);
    w[2] = pack2(Bv[0], Bv[1]); w[3] = pack2(Bv[2], Bv[3]);
    *(i32x4*)(twb + (size_t)tile * 512 + l * 8) = w;
  }
}

// ---------------- main fused kernel: 2-item software pipeline ----------------
// Block = (bc, p, nt-PAIR). Grid 256, 512 threads, 1 block/CU (128 KB LDS).
// A(0) -> tmp0; then 8 store-phases of B(0) each also folding 2 k-steps of
// A(1) (loads issued at phase top, MFMAs at phase bottom -> L3 latency hidden
// under B's MFMA+store work); then acc1 -> tmp1; then 8 phases of B(1).
// Stage-A's HBM-write-idle window is thereby overlapped with B's store stream.
// All state in named scalars / compile-time-indexed arrays (no spills).
__global__ __launch_bounds__(512, 2) void stblis_main(
    const unsigned short* __restrict__ xt, const unsigned short* __restrict__ swb,
    const unsigned short* __restrict__ twb, float* __restrict__ out)
{
  // LDS: tmp0 [0,32K) tmp1 [32K,64K): [64 n][256 u] bf16, slot s=(u>>3)^(n&7)
  //      stg  [64K,128K): two 32 KB buffers, [64 n][32 chunks 16B] f32,
  //                       chunk c at ((c^(n&15))<<4) within the 512B row
  __shared__ __align__(16) char lds[131072];
  char* const tmp0 = lds;
  char* const tmp1 = lds + 32768;
  char* const stgb = lds + 65536;

  const int tid  = threadIdx.x;
  const int lane = tid & 63;
  const int wid  = tid >> 6;
  const int l15  = lane & 15;
  const int l4   = lane >> 4;

  const int bx  = blockIdx.x;
  const int ntp = bx & 3;          // nt pair: items nt0=2*ntp, nt1=2*ntp+1
  const int p   = (bx >> 2) & 3;
  const int bc  = bx >> 4;         // b*4 + c
  const int nt0 = ntp * 2, nt1 = ntp * 2 + 1;
  const int b = bc >> 2, c = bc & 3;

  // stage-A wave roles
  const int wu = wid >> 1;   // u block of 64
  const int wn = wid & 1;    // n block of 32

  const unsigned short* xA  = xt  + (((size_t)(bc * 16 + wu * 4)) * 16) * 512 + lane * 8;
  const unsigned short* sB0 = swb + (((size_t)(p * 32 + nt0 * 4 + wn * 2)) * 16) * 512 + lane * 8;
  const unsigned short* sB1 = swb + (((size_t)(p * 32 + nt1 * 4 + wn * 2)) * 16) * 512 + lane * 8;

  // ---------------- stage A, item 0 ----------------
  f32x4 acc[4][2];
#pragma unroll
  for (int i = 0; i < 4; i++)
#pragma unroll
    for (int j = 0; j < 2; j++) acc[i][j] = {0.f, 0.f, 0.f, 0.f};

  for (int kc = 0; kc < 8; kc++) {
#pragma unroll
    for (int ks = 0; ks < 2; ks++) {
      const int mt2 = kc * 2 + ks;
      bf16x8 af[4], bg[2];
#pragma unroll
      for (int uf = 0; uf < 4; uf++)
        af[uf] = *(const bf16x8*)(xA + ((size_t)uf * 16 + mt2) * 512);
#pragma unroll
      for (int nf = 0; nf < 2; nf++)
        bg[nf] = *(const bf16x8*)(sB0 + ((size_t)nf * 16 + mt2) * 512);
#pragma unroll
      for (int uf = 0; uf < 4; uf++)
#pragma unroll
        for (int nf = 0; nf < 2; nf++)
          acc[uf][nf] = __builtin_amdgcn_mfma_f32_16x16x32_bf16(
              af[uf], bg[nf], acc[uf][nf], 0, 0, 0);
    }
  }
#pragma unroll
  for (int uf = 0; uf < 4; uf++)
#pragma unroll
    for (int nf = 0; nf < 2; nf++) {
      int u0 = wu * 64 + uf * 16 + l4 * 4;
      int n  = wn * 32 + nf * 16 + l15;
      i32x2 w;
      w[0] = pack2(acc[uf][nf][0], acc[uf][nf][1]);
      w[1] = pack2(acc[uf][nf][2], acc[uf][nf][3]);
      *(i32x2*)(tmp0 + n * 512 + (((u0 >> 3) ^ (n & 7)) << 4) + (u0 & 7) * 2) = w;
    }
  __syncthreads();

  // ---------------- stage B roles ----------------
  const int tq = wid >> 1;       // t sixteenth (16 t)
  const int nh = wid & 1;        // n half (32 n)
  const int rowA = nh * 32 + l15;
  const int rowB = rowA + 16;

  float* const outB0 = out + (((size_t)(b * 128 + c * 16 + p * 4)) * 512 + nt0 * 64) * 256;
  float* const outB1 = out + (((size_t)(b * 128 + c * 16 + p * 4)) * 512 + nt1 * 64) * 256;

  bf16x8 bgA[8], bgB[8];

#define LOADBG(dst, ph16)                                                      \
  {                                                                            \
    const int q_ = (ph16) >> 2, tc_ = (ph16) & 3;                              \
    const unsigned short* tA_ =                                                \
        twb + (((size_t)(q_ * 16 + tc_ * 4 + tq)) * 8) * 512 + lane * 8;       \
    _Pragma("unroll")                                                          \
    for (int us_ = 0; us_ < 8; us_++)                                          \
      dst[us_] = *(const bf16x8*)(tA_ + (size_t)us_ * 512);                    \
  }

#define SUB(tmpP, stgP, cur, tcl)                                              \
  {                                                                            \
    f32x4 a20 = {0.f, 0.f, 0.f, 0.f};                                          \
    f32x4 a21 = {0.f, 0.f, 0.f, 0.f};                                          \
    _Pragma("unroll")                                                          \
    for (int us_ = 0; us_ < 8; us_++) {                                        \
      const int slot_ = (us_ * 4 + l4) ^ (l15 & 7);                            \
      bf16x8 af0_ = ldsFrag(tmpP, rowA * 512 + (slot_ << 4));                  \
      bf16x8 af1_ = ldsFrag(tmpP, rowB * 512 + (slot_ << 4));                  \
      a20 = __builtin_amdgcn_mfma_f32_16x16x32_bf16(cur[us_], af0_, a20, 0, 0, 0); \
      a21 = __builtin_amdgcn_mfma_f32_16x16x32_bf16(cur[us_], af1_, a21, 0, 0, 0); \
    }                                                                          \
    const int c32_ = (tcl) * 16 + tq * 4 + l4;                                 \
    *(f32x4*)(stgP + rowA * 512 + ((c32_ ^ (rowA & 15)) << 4)) = a20;          \
    *(f32x4*)(stgP + rowB * 512 + ((c32_ ^ (rowB & 15)) << 4)) = a21;          \
  }

#define STOREPH(stgR, outBase, qv, thv)                                        \
  {                                                                            \
    float* oP_ = (outBase) + (size_t)(qv) * 131072;                            \
    float* oN_ = oP_ + 8388608;                                                \
    _Pragma("unroll")                                                          \
    for (int it_ = 0; it_ < 4; it_++) {                                        \
      int g_ = it_ * 512 + tid;                                                \
      int r_ = g_ >> 5;                                                        \
      int c32_ = g_ & 31;                                                      \
      f32x4 y_ = *(const f32x4*)(stgR + r_ * 512 + ((c32_ ^ (r_ & 15)) << 4)); \
      f32x4 vP_, vN_;                                                          \
      _Pragma("unroll")                                                        \
      for (int j_ = 0; j_ < 4; j_++) {                                         \
        vP_[j_] = fmaxf(y_[j_], 0.f);                                          \
        vN_[j_] = fmaxf(-y_[j_], 0.f);                                         \
      }                                                                        \
      size_t go_ = (size_t)r_ * 256 + (thv) * 128 + c32_ * 4;                  \
      *(f32x4*)(oP_ + go_) = vP_;                                              \
      *(f32x4*)(oN_ + go_) = vN_;                                              \
    }                                                                          \
  }

#define LOADA1(K, F0, F1, F2, F3, G0, G1)                                      \
  {                                                                            \
    const int mt2_ = (K);                                                      \
    F0 = *(const bf16x8*)(xA + ((size_t)0 * 16 + mt2_) * 512);                 \
    F1 = *(const bf16x8*)(xA + ((size_t)1 * 16 + mt2_) * 512);                 \
    F2 = *(const bf16x8*)(xA + ((size_t)2 * 16 + mt2_) * 512);                 \
    F3 = *(const bf16x8*)(xA + ((size_t)3 * 16 + mt2_) * 512);                 \
    G0 = *(const bf16x8*)(sB1 + ((size_t)0 * 16 + mt2_) * 512);                \
    G1 = *(const bf16x8*)(sB1 + ((size_t)1 * 16 + mt2_) * 512);                \
  }

#define MFMA1K(F0, F1, F2, F3, G0, G1)                                         \
  c1_00 = __builtin_amdgcn_mfma_f32_16x16x32_bf16(F0, G0, c1_00, 0, 0, 0);     \
  c1_01 = __builtin_amdgcn_mfma_f32_16x16x32_bf16(F0, G1, c1_01, 0, 0, 0);     \
  c1_10 = __builtin_amdgcn_mfma_f32_16x16x32_bf16(F1, G0, c1_10, 0, 0, 0);     \
  c1_11 = __builtin_amdgcn_mfma_f32_16x16x32_bf16(F1, G1, c1_11, 0, 0, 0);     \
  c1_20 = __builtin_amdgcn_mfma_f32_16x16x32_bf16(F2, G0, c1_20, 0, 0, 0);     \
  c1_21 = __builtin_amdgcn_mfma_f32_16x16x32_bf16(F2, G1, c1_21, 0, 0, 0);     \
  c1_30 = __builtin_amdgcn_mfma_f32_16x16x32_bf16(F3, G0, c1_30, 0, 0, 0);     \
  c1_31 = __builtin_amdgcn_mfma_f32_16x16x32_bf16(F3, G1, c1_31, 0, 0, 0);

#define WT1(ACC, UF, NF)                                                       \
  {                                                                            \
    int u0_ = wu * 64 + (UF) * 16 + l4 * 4;                                    \
    int n_  = wn * 32 + (NF) * 16 + l15;                                       \
    i32x2 w_;                                                                  \
    w_[0] = pack2(ACC[0], ACC[1]);                                             \
    w_[1] = pack2(ACC[2], ACC[3]);                                             \
    *(i32x2*)(tmp1 + n_ * 512 + (((u0_ >> 3) ^ (n_ & 7)) << 4) + (u0_ & 7) * 2) = w_; \
  }

  // item-1 accumulators (named scalars, no arrays -> no scratch risk)
  f32x4 c1_00 = {0.f,0.f,0.f,0.f}, c1_01 = {0.f,0.f,0.f,0.f};
  f32x4 c1_10 = {0.f,0.f,0.f,0.f}, c1_11 = {0.f,0.f,0.f,0.f};
  f32x4 c1_20 = {0.f,0.f,0.f,0.f}, c1_21 = {0.f,0.f,0.f,0.f};
  f32x4 c1_30 = {0.f,0.f,0.f,0.f}, c1_31 = {0.f,0.f,0.f,0.f};
  bf16x8 k0f0, k0f1, k0f2, k0f3, k0g0, k0g1;
  bf16x8 k1f0, k1f1, k1f2, k1f3, k1g0, k1g1;

  LOADBG(bgA, 0);

  // ---------------- B(0) with A(1) folded in ----------------
  for (int ph = 0; ph < 8; ph++) {
    char* stgW = stgb + (ph & 1) * 32768;
    // A1 operand loads issued EARLY (consumed at phase bottom, ~full phase of cover)
    LOADA1(2 * ph,     k0f0, k0f1, k0f2, k0f3, k0g0, k0g1);
    LOADA1(2 * ph + 1, k1f0, k1f1, k1f2, k1f3, k1g0, k1g1);

    LOADBG(bgB, 2 * ph + 1);
    SUB(tmp0, stgW, bgA, 0);
    if (ph < 7) LOADBG(bgA, 2 * ph + 2);
    SUB(tmp0, stgW, bgB, 1);

    // A1 MFMAs (2 k-steps)
    MFMA1K(k0f0, k0f1, k0f2, k0f3, k0g0, k0g1);
    MFMA1K(k1f0, k1f1, k1f2, k1f3, k1g0, k1g1);

    // publish stg: LDS-only drain + raw barrier (stores stay in flight)
    asm volatile("s_waitcnt lgkmcnt(0)\n\ts_barrier" ::: "memory");
    STOREPH(stgW, outB0, ph >> 1, ph & 1);
    // WAR on stgW at ph+2 is fenced by ph+1's barrier (double buffer).
  }

  // ---------------- transition: acc1 -> tmp1 ----------------
  LOADBG(bgA, 0);   // prefetch B(1) phase 0 under the writeback+barrier
  WT1(c1_00, 0, 0) WT1(c1_01, 0, 1)
  WT1(c1_10, 1, 0) WT1(c1_11, 1, 1)
  WT1(c1_20, 2, 0) WT1(c1_21, 2, 1)
  WT1(c1_30, 3, 0) WT1(c1_31, 3, 1)
  asm volatile("s_waitcnt lgkmcnt(0)\n\ts_barrier" ::: "memory");

  // ---------------- B(1) ----------------
  for (int ph = 0; ph < 8; ph++) {
    char* stgW = stgb + (ph & 1) * 32768;
    LOADBG(bgB, 2 * ph + 1);
    SUB(tmp1, stgW, bgA, 0);
    if (ph < 7) LOADBG(bgA, 2 * ph + 2);
    SUB(tmp1, stgW, bgB, 1);
    asm volatile("s_waitcnt lgkmcnt(0)\n\ts_barrier" ::: "memory");
    STOREPH(stgW, outB1, ph >> 1, ph & 1);
  }

#undef LOADBG
#undef SUB
#undef STOREPH
#undef LOADA1
#undef MFMA1K
#undef WT1
}

extern "C" void kernel_launch(void* const* d_in, const int* in_sizes, int n_in,
                              void* d_out, int out_size, void* d_ws, size_t ws_size,
                              hipStream_t stream) {
  (void)in_sizes; (void)n_in; (void)out_size; (void)ws_size;
  const float* x  = (const float*)d_in[0];
  const float* sw = (const float*)d_in[1];
  const float* tw = (const float*)d_in[2];
  float* out = (float*)d_out;

  // workspace (u16 elements): xt 16*16*16*512 (4 MB) | swb 2048*512 (2 MB) | twb 512*512 (0.5 MB)
  unsigned short* xt  = (unsigned short*)d_ws;
  unsigned short* swb = xt + (size_t)16 * 16 * 16 * 512;
  unsigned short* twb = swb + (size_t)2048 * 512;

  cvt_all<<<dim3(1152), dim3(256), 0, stream>>>(x, xt, sw, swb, tw, twb);
  stblis_main<<<dim3(256), dim3(512), 0, stream>>>(xt, swb, twb, out);
}

// Round 14
// 69.688 us; speedup vs baseline: 1.1269x; 1.1269x over previous
//
#include <hip/hip_runtime.h>
#include <hip/hip_bf16.h>

typedef __attribute__((ext_vector_type(8))) short bf16x8;
typedef __attribute__((ext_vector_type(4))) float f32x4;
typedef __attribute__((ext_vector_type(4))) int   i32x4;
typedef __attribute__((ext_vector_type(2))) int   i32x2;

#define DEV static __device__ __forceinline__

DEV unsigned short f2bf(float f) {
  __hip_bfloat16 h = __float2bfloat16(f);
  return __builtin_bit_cast(unsigned short, h);
}
DEV int pack2(float a, float b) {
  return (int)f2bf(a) | ((int)f2bf(b) << 16);
}
DEV bf16x8 ldsFrag(const char* lds, int off) {
  i32x4 v = *(const i32x4*)(lds + off);
  return __builtin_bit_cast(bf16x8, v);
}

// Tiled operand layout: each 1KB tile = one MFMA fragment set for a full wave,
// element order = lane-linear (lane l's 16B at tile_base + l*16B).
// A-frag tile [16 rows][32 k]: lane l -> (row = l&15, k = (l>>4)*8 + j)
// B-frag tile [16 cols][32 k]: identical order.

// ---------------- pre-kernel ----------------
__global__ __launch_bounds__(256) void cvt_all(
    const float* __restrict__ x, unsigned short* __restrict__ xt,
    const float* __restrict__ sw, unsigned short* __restrict__ swb,
    const float* __restrict__ tw, unsigned short* __restrict__ twb)
{
  const int bid = blockIdx.x;
  const int tid = threadIdx.x;
  if (bid < 512) {
    __shared__ unsigned short lt[64][72];
    const int ut = bid & 3;          // u group of 64
    const int mt = (bid >> 2) & 7;   // m group of 64
    const int bc = bid >> 5;         // 0..15
    const int ul = tid & 63;
    const int mr = tid >> 6;
    const float* px = x + ((size_t)bc * 512 + mt * 64) * 256 + ut * 64;
#pragma unroll
    for (int r = 0; r < 16; r++) {
      int m = r * 4 + mr;
      lt[m][ul] = f2bf(px[(size_t)m * 256 + ul]);
    }
    __syncthreads();
    const int t8 = tid >> 5;
    const int a  = t8 & 3;
    const int bb = t8 >> 2;
    const int l0 = tid & 31;
    unsigned short* tilep =
        xt + (((size_t)(bc * 16 + ut * 4 + a)) * 16 + (mt * 2 + bb)) * 512;
#pragma unroll
    for (int h = 0; h < 2; h++) {
      int l = l0 + h * 32;
      int ur = a * 16 + (l & 15);
      int mb = bb * 32 + (l >> 4) * 8;
      i32x4 w;
#pragma unroll
      for (int j = 0; j < 4; j++)
        w[j] = (int)lt[mb + 2 * j][ur] | ((int)lt[mb + 2 * j + 1][ur] << 16);
      *(i32x4*)(tilep + l * 8) = w;
    }
  } else if (bid < 1024) {
    const int tile = (bid - 512) * 4 + (tid >> 6);
    const int l = tid & 63;
    const int mt2 = tile & 15;
    const int nt2 = (tile >> 4) & 31;
    const int p   = tile >> 9;
    const float* ps = sw + ((size_t)p * 512 + nt2 * 16 + (l & 15)) * 512
                         + mt2 * 32 + (l >> 4) * 8;
    f32x4 A = ((const f32x4*)ps)[0], Bv = ((const f32x4*)ps)[1];
    i32x4 w;
    w[0] = pack2(A[0], A[1]);  w[1] = pack2(A[2], A[3]);
    w[2] = pack2(Bv[0], Bv[1]); w[3] = pack2(Bv[2], Bv[3]);
    *(i32x4*)(swb + (size_t)tile * 512 + l * 8) = w;
  } else {
    const int tile = (bid - 1024) * 4 + (tid >> 6);
    const int l = tid & 63;
    const int ut2 = tile & 7;
    const int tt2 = (tile >> 3) & 15;
    const int q   = tile >> 7;
    const float* pt = tw + ((size_t)q * 256 + tt2 * 16 + (l & 15)) * 256
                         + ut2 * 32 + (l >> 4) * 8;
    f32x4 A = ((const f32x4*)pt)[0], Bv = ((const f32x4*)pt)[1];
    i32x4 w;
    w[0] = pack2(A[0], A[1]);  w[1] = pack2(A[2], A[3]);
    w[2] = pack2(Bv[0], Bv[1]); w[3] = pack2(Bv[2], Bv[3]);
    *(i32x4*)(twb + (size_t)tile * 512 + l * 8) = w;
  }
}

// ---------------- main fused kernel ----------------
// B=4, C=4, N=512, T=256, K(P)=4, J(Q)=4
// Block = (bc, p, n-tile of 64). Grid 512, 512 threads.
// Stage A: tmp[n][u] = sum_m S_p[n0+n][m]*X[m][u] (acc = tmp^T frags; tiled loads)
//   -> tmp in LDS [0,32768), then HOISTED to registers (afr[8][2], 64 VGPR).
// Stage B: 16 phases (q,tc); per phase: 16 reg-only MFMA -> ds_write y-tile
//   (staging DOUBLE-BUFFERED, aliased over dead tmp) -> barrier -> full-line stores.
//   Next phase's Tq fragments prefetched from global one phase ahead.
__global__ __launch_bounds__(512, 4) void stblis_main(
    const unsigned short* __restrict__ xt, const unsigned short* __restrict__ swb,
    const unsigned short* __restrict__ twb, float* __restrict__ out)
{
  // LDS: phase 1: tmp[n=64][u=256] bf16, row 512B, slot s=(u>>3)^(n&7)  [0,32768)
  //      phase 2: stg0 [0,16384), stg1 [16384,32768):
  //               y f32 [64 n][16 chunks of 16B], chunk c at (c^(n&7))*16
  __shared__ __align__(16) char lds[32768];

  const int tid  = threadIdx.x;
  const int lane = tid & 63;
  const int wid  = tid >> 6;
  const int l15  = lane & 15;
  const int l4   = lane >> 4;

  const int bx = blockIdx.x;
  const int nt = bx & 7;          // n-tile of 64
  const int p  = (bx >> 3) & 3;
  const int bc = bx >> 5;         // b*4 + c
  const int n0 = nt * 64;
  const int b = bc >> 2, c = bc & 3;

  // ---------------- stage A ----------------
  const int wu = wid >> 1;   // u block of 64
  const int wn = wid & 1;    // n block of 32

  f32x4 acc[4][2];
#pragma unroll
  for (int i = 0; i < 4; i++)
#pragma unroll
    for (int j = 0; j < 2; j++) acc[i][j] = {0.f, 0.f, 0.f, 0.f};

  const unsigned short* xA = xt  + (((size_t)(bc * 16 + wu * 4)) * 16) * 512 + lane * 8;
  const unsigned short* sB = swb + (((size_t)(p * 32 + nt * 4 + wn * 2)) * 16) * 512 + lane * 8;

  for (int kc = 0; kc < 8; kc++) {
#pragma unroll
    for (int ks = 0; ks < 2; ks++) {
      const int mt2 = kc * 2 + ks;
      bf16x8 af[4], bg[2];
#pragma unroll
      for (int uf = 0; uf < 4; uf++)
        af[uf] = *(const bf16x8*)(xA + ((size_t)uf * 16 + mt2) * 512);
#pragma unroll
      for (int nf = 0; nf < 2; nf++)
        bg[nf] = *(const bf16x8*)(sB + ((size_t)nf * 16 + mt2) * 512);
#pragma unroll
      for (int uf = 0; uf < 4; uf++)
#pragma unroll
        for (int nf = 0; nf < 2; nf++)
          acc[uf][nf] = __builtin_amdgcn_mfma_f32_16x16x32_bf16(
              af[uf], bg[nf], acc[uf][nf], 0, 0, 0);
    }
  }

  // acc (tmp^T frags: row=u, col=n) -> LDS tmp[n][u] bf16 (swizzled)
#pragma unroll
  for (int uf = 0; uf < 4; uf++)
#pragma unroll
    for (int nf = 0; nf < 2; nf++) {
      int u0 = wu * 64 + uf * 16 + l4 * 4;
      int n  = wn * 32 + nf * 16 + l15;
      i32x2 w;
      w[0] = pack2(acc[uf][nf][0], acc[uf][nf][1]);
      w[1] = pack2(acc[uf][nf][2], acc[uf][nf][3]);
      *(i32x2*)(lds + n * 512 + (((u0 >> 3) ^ (n & 7)) << 4) + (u0 & 7) * 2) = w;
    }
  __syncthreads();

  // ---------------- stage B ----------------
  const int tq = wid >> 1;       // t quarter (16 t)
  const int nh = wid & 1;        // n half (32 n)

#define LOADBG(dst, ph)                                                        \
  {                                                                            \
    const int q_ = (ph) >> 2, tc_ = (ph) & 3;                                  \
    const unsigned short* tA_ =                                                \
        twb + (((size_t)(q_ * 16 + tc_ * 4 + tq)) * 8) * 512 + lane * 8;       \
    _Pragma("unroll")                                                          \
    for (int us = 0; us < 8; us++)                                             \
      dst[us] = *(const bf16x8*)(tA_ + (size_t)us * 512);                      \
  }

  // prefetch phase-0 bg (global, overlaps the hoist ds_reads below)
  bf16x8 bgA[8], bgB[8];
  LOADBG(bgA, 0);

  // hoist tmp A-frags to registers: phase-invariant (depend on us, nf only)
  bf16x8 afr[8][2];
#pragma unroll
  for (int us = 0; us < 8; us++)
#pragma unroll
    for (int nf = 0; nf < 2; nf++) {
      int n = nh * 32 + nf * 16 + l15;
      afr[us][nf] = ldsFrag(lds, n * 512 + (((us * 4 + l4) ^ (n & 7)) << 4));
    }
  __syncthreads();   // tmp now dead; staging buffers alias it

  char* const stg0 = lds;
  char* const stg1 = lds + 16384;

  auto body = [&](int ph, bf16x8 (&bg)[8], char* stgW) {
    const int q  = ph >> 2;
    const int tc = ph & 3;
    f32x4 a2[2];
    a2[0] = {0.f, 0.f, 0.f, 0.f};
    a2[1] = {0.f, 0.f, 0.f, 0.f};
#pragma unroll
    for (int us = 0; us < 8; us++) {
      a2[0] = __builtin_amdgcn_mfma_f32_16x16x32_bf16(bg[us], afr[us][0], a2[0], 0, 0, 0);
      a2[1] = __builtin_amdgcn_mfma_f32_16x16x32_bf16(bg[us], afr[us][1], a2[1], 0, 0, 0);
    }
    // stage y-frags to LDS: lane's 4 regs = 4 consecutive t -> one 16B chunk
#pragma unroll
    for (int nf = 0; nf < 2; nf++) {
      int n = nh * 32 + nf * 16 + l15;
      int c16 = tq * 4 + l4;
      *(f32x4*)(stgW + n * 256 + ((c16 ^ (n & 7)) << 4)) = a2[nf];
    }
    __syncthreads();
    // linear store: lanes 0..15 cover a full 256B row (2 full 128B lines)
    float* outQP = out + ((size_t)(b * 128 + c * 16 + p * 4 + q) * 512 + n0) * 256;
    float* outQN = outQP + (size_t)64 * 512 * 256;
#pragma unroll
    for (int h = 0; h < 2; h++) {
      int cc  = tid + h * 512;
      int r   = cc >> 4;
      int o16 = cc & 15;
      f32x4 y = *(const f32x4*)(stgW + r * 256 + ((o16 ^ (r & 7)) << 4));
      f32x4 vP, vN;
#pragma unroll
      for (int j = 0; j < 4; j++) {
        vP[j] = fmaxf(y[j], 0.f);
        vN[j] = fmaxf(-y[j], 0.f);
      }
      size_t go = (size_t)r * 256 + tc * 64 + o16 * 4;
      *(f32x4*)(outQP + go) = vP;
      *(f32x4*)(outQN + go) = vN;
    }
    // WAR on stgW (phase ph+2's writes) is fenced by phase ph+1's barrier
  };

  for (int ph2 = 0; ph2 < 8; ph2++) {
    const int ph = ph2 * 2;
    LOADBG(bgB, ph + 1);          // prefetch: latency hides under body(ph)
    body(ph, bgA, stg0);
    if (ph2 < 7) LOADBG(bgA, ph + 2);
    body(ph + 1, bgB, stg1);
  }
#undef LOADBG
}

extern "C" void kernel_launch(void* const* d_in, const int* in_sizes, int n_in,
                              void* d_out, int out_size, void* d_ws, size_t ws_size,
                              hipStream_t stream) {
  (void)in_sizes; (void)n_in; (void)out_size; (void)ws_size;
  const float* x  = (const float*)d_in[0];
  const float* sw = (const float*)d_in[1];
  const float* tw = (const float*)d_in[2];
  float* out = (float*)d_out;

  // workspace (u16 elements): xt 16*16*16*512 (4 MB) | swb 2048*512 (2 MB) | twb 512*512 (0.5 MB)
  unsigned short* xt  = (unsigned short*)d_ws;
  unsigned short* swb = xt + (size_t)16 * 16 * 16 * 512;
  unsigned short* twb = swb + (size_t)2048 * 512;

  cvt_all<<<dim3(1152), dim3(256), 0, stream>>>(x, xt, sw, swb, tw, twb);
  stblis_main<<<dim3(512), dim3(512), 0, stream>>>(xt, swb, twb, out);
}